// Round 8
// baseline (617.590 us; speedup 1.0000x reference)
//
#include <hip/hip_runtime.h>

#define MAXD 192
#define NCH  16

#define RFL_I(x) __builtin_amdgcn_readfirstlane(x)
#define RFL_F(x) __int_as_float(__builtin_amdgcn_readfirstlane(__float_as_int(x)))
#define RDL(v,k) __int_as_float(__builtin_amdgcn_readlane(__float_as_int(v), (k)))
#define LOADF(base, boff) (*(const float*)((base) + (boff)))

// One block per (point n = blockIdx.x, level j = blockIdx.y).
// Waves 0-2: pass-1 (scale 1) disparity chunks [0,64),[64,128),[128,192).
// Wave 3:   pass-0 (scale 4, D=48), level j+8.
// Wave-private LDS strips; only block-wide barrier is the val4 handoff.
// All bilinear weights/masks are block constants (coords = p + s*integer).
// Addressing: per-lane column BYTE offsets (named VGPRs, loop-invariant) +
// wave-uniform row byte offsets pinned to SGPR via readfirstlane -> strip
// loads are saddr-form with zero per-load VALU. NO register arrays live
// across the channel loop (R5/R6 scratch-spill lesson).
__global__ __launch_bounds__(256, 8) void pbm_kernel(
    const float* __restrict__ lfeat,   // (16,1,16,H,W)
    const float* __restrict__ rfeat,
    const float* __restrict__ points,  // (1,N,2)
    const int* __restrict__ pW, const int* __restrict__ pH,
    float* __restrict__ out)           // (1,N,192,8)
{
    const int W = RFL_I(*pW), H = RFL_I(*pH);
    const int HW = W * H;
    const int n   = blockIdx.x;
    const int j   = blockIdx.y;        // linear wg = n + N*j, N%8==0 -> same-n same XCD
    const int tid = threadIdx.x;
    const int wv  = tid >> 6;
    const int l   = tid & 63;

    const float pxr = points[2 * n];
    const float pyr = points[2 * n + 1];
    const float pxf = floorf(pxr), pyf = floorf(pyr);
    const float fx  = RFL_F(pxr - pxf);
    const float fy  = RFL_F(pyr - pyf);
    const int   x0i = RFL_I((int)pxf);
    const int   y0i = RFL_I((int)pyf);

    __shared__ float sv[4][5][68];     // per-wave right strip
    __shared__ float val4[48];

    const bool p0     = (wv == 3);
    const int  s_     = RFL_I(p0 ? 4 : 1);
    const int  lvl    = RFL_I(p0 ? j + 8 : j);
    const int  off    = RFL_I(p0 ? 49 : wv * 64 + 65);
    const int  DC     = RFL_I(p0 ? 48 : 64);
    const int  stageN = RFL_I(p0 ? 52 : 64);

    // ---- per-lane strip column byte offsets + folded x-weights ----
    const int   cx   = x0i + s_ * (l - off);
    const int   cbB0 = min(max(cx, 0), W - 1) * 4;
    const int   cbB1 = min(max(cx + 1, 0), W - 1) * 4;
    const float ax0  = (((unsigned)cx       < (unsigned)W) ? 1.0f : 0.0f) * (1.0f - fx);
    const float ax1  = (((unsigned)(cx + 1) < (unsigned)W) ? 1.0f : 0.0f) * fx;

    // ---- wave-uniform row byte offsets + y-weights (SGPR via RFL) ----
#define ROWC(K, RB0, RB1, BY0, BY1)                                              \
    const int   RB0 = RFL_I(min(max(y0i + s_ * ((K) - 2), 0), H - 1) * W * 4);   \
    const int   RB1 = RFL_I(min(max(y0i + s_ * ((K) - 2) + 1, 0), H - 1) * W * 4);\
    const float BY0 = RFL_F(((unsigned)(y0i + s_ * ((K) - 2))     < (unsigned)H) \
                            ? (1.0f - fy) : 0.0f);                               \
    const float BY1 = RFL_F(((unsigned)(y0i + s_ * ((K) - 2) + 1) < (unsigned)H) \
                            ? fy : 0.0f);
    ROWC(0, rb0_0, rb1_0, by0_0, by1_0)
    ROWC(1, rb0_1, rb1_1, by0_1, by1_1)
    ROWC(2, rb0_2, rb1_2, by0_2, by1_2)
    ROWC(3, rb0_3, rb1_3, by0_3, by1_3)
    ROWC(4, rb0_4, rb1_4, by0_4, by1_4)
#undef ROWC

    // ---- cleanup taps (pass-1 waves, lanes<20): col 64+(l&3), row l>>2 ----
    const int   dyc  = min(l >> 2, 4);
    const int   dcol = 64 + (l & 3);
    const int   dcx  = x0i + s_ * (dcol - off);
    const int   dbB0 = min(max(dcx, 0), W - 1) * 4;
    const int   dbB1 = min(max(dcx + 1, 0), W - 1) * 4;
    const float dax0 = (((unsigned)dcx       < (unsigned)W) ? 1.0f : 0.0f) * (1.0f - fx);
    const float dax1 = (((unsigned)(dcx + 1) < (unsigned)W) ? 1.0f : 0.0f) * fx;
    const int   dyr  = y0i + s_ * (dyc - 2);
    const float dwy0 = ((unsigned)dyr       < (unsigned)H) ? (1.0f - fy) : 0.0f;
    const float dwy1 = ((unsigned)(dyr + 1) < (unsigned)H) ? fy : 0.0f;
    // combined per-lane byte offsets (row + col), loop-invariant named VGPRs
    const int   vo0 = min(max(dyr, 0), H - 1) * W * 4 + dbB0;
    const int   vo1 = min(max(dyr, 0), H - 1) * W * 4 + dbB1;
    const int   vo2 = min(max(dyr + 1, 0), H - 1) * W * 4 + dbB0;
    const int   vo3 = min(max(dyr + 1, 0), H - 1) * W * 4 + dbB1;

    // ---- left window taps (lanes 0..24 meaningful) ----
    const int   lq  = min(l, 24);
    const int   lyy = lq / 5;
    const int   lxx = lq - lyy * 5;
    const int   lx  = x0i + s_ * (lxx - 2);
    const int   ly  = y0i + s_ * (lyy - 2);
    const float lax0 = (((unsigned)lx       < (unsigned)W) ? 1.0f : 0.0f) * (1.0f - fx);
    const float lax1 = (((unsigned)(lx + 1) < (unsigned)W) ? 1.0f : 0.0f) * fx;
    const float lwy0 = ((unsigned)ly       < (unsigned)H) ? (1.0f - fy) : 0.0f;
    const float lwy1 = ((unsigned)(ly + 1) < (unsigned)H) ? fy : 0.0f;
    const int   lo0 = min(max(ly, 0), H - 1) * W * 4 + min(max(lx, 0), W - 1) * 4;
    const int   lo1 = min(max(ly, 0), H - 1) * W * 4 + min(max(lx + 1, 0), W - 1) * 4;
    const int   lo2 = min(max(ly + 1, 0), H - 1) * W * 4 + min(max(lx, 0), W - 1) * 4;
    const int   lo3 = min(max(ly + 1, 0), H - 1) * W * 4 + min(max(lx + 1, 0), W - 1) * 4;

    const char* Rp = (const char*)rfeat + (size_t)(lvl * NCH) * HW * 4;
    const char* Lp = (const char*)lfeat + (size_t)(lvl * NCH) * HW * 4;
    const size_t HW4 = (size_t)HW * 4;

    float acc = 0.0f;
#pragma unroll 1
    for (int c = 0; c < NCH; ++c, Rp += HW4, Lp += HW4) {
        if (l < stageN) {
#define STRIPROW(K, RB0, RB1, BY0, BY1) {                                  \
            float v00 = LOADF(Rp + RB0, cbB0), v01 = LOADF(Rp + RB0, cbB1);\
            float v10 = LOADF(Rp + RB1, cbB0), v11 = LOADF(Rp + RB1, cbB1);\
            float t = fmaf(ax0, v00, ax1 * v01);                           \
            float b = fmaf(ax0, v10, ax1 * v11);                           \
            sv[wv][K][l] = fmaf(BY0, t, BY1 * b); }
            STRIPROW(0, rb0_0, rb1_0, by0_0, by1_0)
            STRIPROW(1, rb0_1, rb1_1, by0_1, by1_1)
            STRIPROW(2, rb0_2, rb1_2, by0_2, by1_2)
            STRIPROW(3, rb0_3, rb1_3, by0_3, by1_3)
            STRIPROW(4, rb0_4, rb1_4, by0_4, by1_4)
#undef STRIPROW
        }
        if (!p0 && l < 20) {
            float v00 = LOADF(Rp, vo0), v01 = LOADF(Rp, vo1);
            float v10 = LOADF(Rp, vo2), v11 = LOADF(Rp, vo3);
            float t = fmaf(dax0, v00, dax1 * v01);
            float b = fmaf(dax0, v10, dax1 * v11);
            sv[wv][dyc][dcol] = fmaf(dwy0, t, dwy1 * b);
        }
        float lval;
        {
            float v00 = LOADF(Lp, lo0), v01 = LOADF(Lp, lo1);
            float v10 = LOADF(Lp, lo2), v11 = LOADF(Lp, lo3);
            float t = fmaf(lax0, v00, lax1 * v01);
            float b = fmaf(lax0, v10, lax1 * v11);
            lval = fmaf(lwy0, t, lwy1 * b);
        }

        // broadcast left window into wave-uniform scalars (SGPRs)
        float sk00 = RDL(lval, 0),  sk01 = RDL(lval, 1),  sk02 = RDL(lval, 2);
        float sk03 = RDL(lval, 3),  sk04 = RDL(lval, 4);
        float sk05 = RDL(lval, 5),  sk06 = RDL(lval, 6),  sk07 = RDL(lval, 7);
        float sk08 = RDL(lval, 8),  sk09 = RDL(lval, 9);
        float sk10 = RDL(lval, 10), sk11 = RDL(lval, 11), sk12 = RDL(lval, 12);
        float sk13 = RDL(lval, 13), sk14 = RDL(lval, 14);
        float sk15 = RDL(lval, 15), sk16 = RDL(lval, 16), sk17 = RDL(lval, 17);
        float sk18 = RDL(lval, 18), sk19 = RDL(lval, 19);
        float sk20 = RDL(lval, 20), sk21 = RDL(lval, 21), sk22 = RDL(lval, 22);
        float sk23 = RDL(lval, 23), sk24 = RDL(lval, 24);

        if (l < DC) {
            float a0 = 0.f, a1 = 0.f;
            {
                const float* rp = &sv[wv][0][DC - 1 - l];
                a0 += fabsf(sk00 - rp[0]); a1 += fabsf(sk01 - rp[1]);
                a0 += fabsf(sk02 - rp[2]); a1 += fabsf(sk03 - rp[3]);
                a0 += fabsf(sk04 - rp[4]);
            }
            {
                const float* rp = &sv[wv][1][DC - 1 - l];
                a0 += fabsf(sk05 - rp[0]); a1 += fabsf(sk06 - rp[1]);
                a0 += fabsf(sk07 - rp[2]); a1 += fabsf(sk08 - rp[3]);
                a0 += fabsf(sk09 - rp[4]);
            }
            {
                const float* rp = &sv[wv][2][DC - 1 - l];
                a0 += fabsf(sk10 - rp[0]); a1 += fabsf(sk11 - rp[1]);
                a0 += fabsf(sk12 - rp[2]); a1 += fabsf(sk13 - rp[3]);
                a0 += fabsf(sk14 - rp[4]);
            }
            {
                const float* rp = &sv[wv][3][DC - 1 - l];
                a0 += fabsf(sk15 - rp[0]); a1 += fabsf(sk16 - rp[1]);
                a0 += fabsf(sk17 - rp[2]); a1 += fabsf(sk18 - rp[3]);
                a0 += fabsf(sk19 - rp[4]);
            }
            {
                const float* rp = &sv[wv][4][DC - 1 - l];
                a0 += fabsf(sk20 - rp[0]); a1 += fabsf(sk21 - rp[1]);
                a0 += fabsf(sk22 - rp[2]); a1 += fabsf(sk23 - rp[3]);
                a0 += fabsf(sk24 - rp[4]);
            }
            acc += a0 + a1;
        }
    }

    if (p0 && l < 48)
        val4[l] = 1.0f - expf(-acc * (1.0f / 400.0f));

    __syncthreads();                     // the ONLY block-wide barrier

    if (tid < MAXD) {                    // waves 0-2: d == tid
        float v1  = 1.0f - expf(-acc * (1.0f / 400.0f));
        float pos = (float)tid * (47.0f / 191.0f);
        float i0f = floorf(pos);
        int   i0  = (int)i0f;
        float w   = pos - i0f;
        int   i1  = min(i0 + 1, 47);
        float up  = val4[i0] + w * (val4[i1] - val4[i0]);
        out[((size_t)n * MAXD + tid) * 8 + j] = v1 + up;
    }
}

extern "C" void kernel_launch(void* const* d_in, const int* in_sizes, int n_in,
                              void* d_out, int out_size, void* d_ws, size_t ws_size,
                              hipStream_t stream) {
    const float* lf  = (const float*)d_in[0];
    const float* rf  = (const float*)d_in[1];
    const float* pts = (const float*)d_in[2];
    const int*   pW  = (const int*)d_in[3];
    const int*   pH  = (const int*)d_in[4];
    float* out = (float*)d_out;

    const int N = in_sizes[2] / 2;       // (B=1, N, 2)
    pbm_kernel<<<dim3(N, 8), 256, 0, stream>>>(lf, rf, pts, pW, pH, out);
}